// Round 10
// baseline (48.298 us; speedup 1.0000x reference)
//
#include <hip/hip_runtime.h>
#include <hip/hip_bf16.h>
#include <math.h>

#define NH 16
#define SL 2048
#define DM 128

typedef float f32x4 __attribute__((ext_vector_type(4)));
typedef short s16x8 __attribute__((ext_vector_type(8)));
typedef short s16x4 __attribute__((ext_vector_type(4)));
typedef int   i32x4 __attribute__((ext_vector_type(4)));

static __device__ __forceinline__ unsigned short f2bfu(float f) {
  __hip_bfloat16 h = __float2bfloat16(f);
  return (unsigned short)__builtin_bit_cast(short, h);
}
static __device__ __forceinline__ short f2bf(float f) {
  __hip_bfloat16 h = __float2bfloat16(f);
  return __builtin_bit_cast(short, h);
}
static __device__ __forceinline__ unsigned pack2(float lo, float hi) {
  return (unsigned)f2bfu(lo) | ((unsigned)f2bfu(hi) << 16);
}
static __device__ __forceinline__ float bf2f(short s) {
  unsigned u = ((unsigned)(unsigned short)s) << 16;
  return __builtin_bit_cast(float, u);
}

// 4-wave block = 64 q-rows. KV tile 64, K row-major bf16 swizzled, V^T bf16
// swizzled. Swapped QK^T (mfma(K,Q) -> S^T). Reg-staged dbuf, ONE barrier per
// tile, P->PV in-register via shuffles. Split-KV: q-blocks with n>=5 tiles run
// as two partial blocks (z=0/1, chains <= 4); partial acc (unnormalized, bf16)
// goes to pacc, per-row (m,l) stashed in out[row][0..3]; merge kernel combines.
__global__ __launch_bounds__(256) void attn_part(
    const float* __restrict__ qg,
    const float* __restrict__ kg,
    const float* __restrict__ vg,
    const int* __restrict__ offs, int n_off,
    float* __restrict__ out,
    char* __restrict__ pacc, int allow_split)
{
  __shared__ __align__(16) char Kb[2][16384];
  __shared__ __align__(16) char Vb[2][16384];

  const int t    = threadIdx.x;
  const int lane = t & 63;
  const int w    = t >> 6;
  const int col  = lane & 15;
  const int g    = lane >> 4;

  const int blk = blockIdx.x;
  const int z   = blk >> 9;           // 0 for grid<=512
  const int i   = (blk >> 4) & 31;
  const int h   = blk & 15;
  const int qb  = 31 - i;             // biggest chains dispatch first
  const int q0  = qb * 64;

  const float* qh = qg + (size_t)h * SL * DM;
  const float* kh = kg + (size_t)h * SL * DM;
  const float* vh = vg + (size_t)h * SL * DM;

  const float scale = 0.08838834764831843f; // 1/sqrt(128)

  const int qrow = q0 + 16 * w + col;

  // offsets: parallel predicated loads (sorted ascending -> max of o<=pos)
  int ov[8];
  #pragma unroll
  for (int ii = 0; ii < 8; ++ii) ov[ii] = (ii < n_off) ? offs[ii] : 0x7fffffff;
  int qstart = 0, kv_lo = 0;
  #pragma unroll
  for (int ii = 0; ii < 8; ++ii) {
    if (ov[ii] <= qrow) qstart = max(qstart, ov[ii]);
    if (ov[ii] <= q0)   kv_lo  = max(kv_lo, ov[ii]);
  }
  const int n = ((q0 + 64) - kv_lo) >> 6;      // total KV tiles for this q-block

  const bool split = allow_split && (n >= 5);
  if (!split && z) return;                     // whole block exits (no barriers yet)
  int tA = 0, tN = n;
  if (split) {
    const int nA = (n + 1) >> 1;
    if (z) { tA = nA; tN = n - nA; } else { tN = nA; }
  }
  const int kvb = kv_lo + (tA << 6);           // this block's KV base

  // Q fragment, pre-scaled. Lane holds [row=col][k=8g+j] per 32-k group kk.
  s16x8 qf[4];
  #pragma unroll
  for (int kk = 0; kk < 4; ++kk) {
    const float* qp = qh + (size_t)qrow * DM + 32 * kk + 8 * g;
    f32x4 lo = *(const f32x4*)qp;
    f32x4 hi = *(const f32x4*)(qp + 4);
    s16x8 f;
    f[0] = f2bf(lo[0] * scale); f[1] = f2bf(lo[1] * scale);
    f[2] = f2bf(lo[2] * scale); f[3] = f2bf(lo[3] * scale);
    f[4] = f2bf(hi[0] * scale); f[5] = f2bf(hi[1] * scale);
    f[6] = f2bf(hi[2] * scale); f[7] = f2bf(hi[3] * scale);
    qf[kk] = f;
  }

  f32x4 acc[8];
  #pragma unroll
  for (int dt = 0; dt < 8; ++dt) { f32x4 zv = {0.f, 0.f, 0.f, 0.f}; acc[dt] = zv; }
  float m_ = -1e30f, l_ = 0.f;

  // staging: thread covers K rows r0+8i (cols d0..d0+3) and V rows r0*4+32k+j
  const int d0  = (t & 31) * 4;
  const int r0  = t >> 5;
  const int rot = (t >> 1) & 3;
  f32x4 kr[8], vr[8];

#define LOADT(T) do {                                                         \
    const float* _ks = kh + (size_t)(kvb + ((T) << 6)) * DM;                  \
    const float* _vs = vh + (size_t)(kvb + ((T) << 6)) * DM;                  \
    _Pragma("unroll")                                                         \
    for (int _i = 0; _i < 8; ++_i)                                            \
      kr[_i] = *(const f32x4*)(_ks + (size_t)(r0 + 8 * _i) * DM + d0);        \
    _Pragma("unroll")                                                         \
    for (int _k = 0; _k < 2; ++_k) {                                          \
      _Pragma("unroll")                                                       \
      for (int _j = 0; _j < 4; ++_j)                                          \
        vr[_k * 4 + _j] =                                                     \
          *(const f32x4*)(_vs + (size_t)(r0 * 4 + 32 * _k + _j) * DM + d0);   \
    }                                                                         \
  } while (0)

#define WRITEKV(B) do {                                                       \
    _Pragma("unroll")                                                         \
    for (int _i = 0; _i < 8; ++_i) {                                          \
      int _r = r0 + 8 * _i;                                                   \
      s16x4 _b;                                                               \
      _b[0] = f2bf(kr[_i][0]); _b[1] = f2bf(kr[_i][1]);                       \
      _b[2] = f2bf(kr[_i][2]); _b[3] = f2bf(kr[_i][3]);                       \
      *(s16x4*)(&Kb[B][0] + ((_r * 256 + d0 * 2) ^ ((_r & 7) << 4))) = _b;    \
    }                                                                         \
    _Pragma("unroll")                                                         \
    for (int _k = 0; _k < 2; ++_k) {                                          \
      int _k0 = r0 * 4 + 32 * _k;                                             \
      _Pragma("unroll")                                                       \
      for (int _di = 0; _di < 4; ++_di) {                                     \
        int _dd = (_di + rot) & 3;                                            \
        int _d  = d0 + _dd;                                                   \
        s16x4 _b;                                                             \
        _b[0] = f2bf(vr[_k * 4 + 0][_dd]); _b[1] = f2bf(vr[_k * 4 + 1][_dd]); \
        _b[2] = f2bf(vr[_k * 4 + 2][_dd]); _b[3] = f2bf(vr[_k * 4 + 3][_dd]); \
        *(s16x4*)(&Vb[B][0] + ((_d * 128 + _k0 * 2) ^ ((_d & 7) << 4))) = _b; \
      }                                                                       \
    }                                                                         \
  } while (0)

  // prologue: stage tile 0 into buffer 0
  LOADT(0);
  WRITEKV(0);
  int cur = 0;

  // P-shuffle source lanes: target (col,g) pulls from col+32*(g&1) and +16
  const int srcA = col + 32 * (g & 1);
  const int srcB = srcA + 16;
  const bool hi2 = (g >> 1) != 0;

  for (int it = 0; it < tN; ++it) {
    const int kv0 = kvb + (it << 6);
    __syncthreads();                       // release writes, acquire buf[cur]

    const bool pre = (it + 1 < tN);
    if (pre) LOADT(it + 1);                // issue next-tile global loads early
    __builtin_amdgcn_sched_barrier(0);     // pin loads before compute

    // ---- QK^T (swapped): st[kt] = K_tile_kt . Q^T -> S^T[k][q] ----
    f32x4 st[4];
    #pragma unroll
    for (int kt = 0; kt < 4; ++kt) { f32x4 zv = {0.f, 0.f, 0.f, 0.f}; st[kt] = zv; }
    __builtin_amdgcn_s_setprio(1);
    #pragma unroll
    for (int kt = 0; kt < 4; ++kt) {
      int row = kt * 16 + col;
      #pragma unroll
      for (int kk = 0; kk < 4; ++kk) {
        s16x8 kf = *(const s16x8*)(&Kb[cur][0] + ((row * 256 + 64 * kk + 16 * g) ^ ((row & 7) << 4)));
        st[kt] = __builtin_amdgcn_mfma_f32_16x16x32_bf16(kf, qf[kk], st[kt], 0, 0, 0);
      }
    }
    __builtin_amdgcn_s_setprio(0);

    // ---- mask (skipped for interior tiles) + online softmax ----
    const bool needmask = __any((kv0 + 63 > qrow) || (kv0 < qstart));
    if (needmask) {
      #pragma unroll
      for (int kt = 0; kt < 4; ++kt) {
        #pragma unroll
        for (int r = 0; r < 4; ++r) {
          int kpos = kv0 + kt * 16 + 4 * g + r;
          bool ok = (kpos <= qrow) && (kpos >= qstart);
          st[kt][r] = ok ? st[kt][r] : -3.0e38f;
        }
      }
    }
    float cm = -3.0e38f;
    #pragma unroll
    for (int kt = 0; kt < 4; ++kt) {
      #pragma unroll
      for (int r = 0; r < 4; ++r) cm = fmaxf(cm, st[kt][r]);
    }
    cm = fmaxf(cm, __shfl_xor(cm, 16));
    cm = fmaxf(cm, __shfl_xor(cm, 32));
    float mn = fmaxf(m_, cm);
    float al = __expf(m_ - mn);
    m_ = mn;
    float psum = 0.f;
    unsigned w01[4], w23[4];
    #pragma unroll
    for (int kt = 0; kt < 4; ++kt) {
      float p0 = __expf(st[kt][0] - mn);
      float p1 = __expf(st[kt][1] - mn);
      float p2 = __expf(st[kt][2] - mn);
      float p3 = __expf(st[kt][3] - mn);
      psum += (p0 + p1) + (p2 + p3);
      w01[kt] = pack2(p0, p1);
      w23[kt] = pack2(p2, p3);
    }
    psum += __shfl_xor(psum, 16);
    psum += __shfl_xor(psum, 32);
    l_ = l_ * al + psum;

    // ---- rescale O by alpha (per output row 4g+r) ----
    #pragma unroll
    for (int r = 0; r < 4; ++r) {
      float ar = __shfl(al, 4 * g + r);
      #pragma unroll
      for (int dt = 0; dt < 8; ++dt) acc[dt][r] *= ar;
    }

    // ---- PV: A-frag assembled in-register via shuffles; acc += P . V ----
    __builtin_amdgcn_s_setprio(1);
    #pragma unroll
    for (int ksel = 0; ksel < 2; ++ksel) {
      unsigned a0 = __shfl(w01[2 * ksel], srcA);
      unsigned a1 = __shfl(w01[2 * ksel + 1], srcA);
      unsigned b0 = __shfl(w23[2 * ksel], srcA);
      unsigned b1 = __shfl(w23[2 * ksel + 1], srcA);
      unsigned c0 = __shfl(w01[2 * ksel], srcB);
      unsigned c1 = __shfl(w01[2 * ksel + 1], srcB);
      unsigned e0 = __shfl(w23[2 * ksel], srcB);
      unsigned e1 = __shfl(w23[2 * ksel + 1], srcB);
      i32x4 uu;
      uu[0] = (int)(hi2 ? a1 : a0);
      uu[1] = (int)(hi2 ? b1 : b0);
      uu[2] = (int)(hi2 ? c1 : c0);
      uu[3] = (int)(hi2 ? e1 : e0);
      s16x8 pa = __builtin_bit_cast(s16x8, uu);
      #pragma unroll
      for (int dt = 0; dt < 8; ++dt) {
        int d = dt * 16 + col;
        s16x8 vf = *(const s16x8*)(&Vb[cur][0] + ((d * 128 + 64 * ksel + 16 * g) ^ ((d & 7) << 4)));
        acc[dt] = __builtin_amdgcn_mfma_f32_16x16x32_bf16(pa, vf, acc[dt], 0, 0, 0);
      }
    }
    __builtin_amdgcn_s_setprio(0);

    // ---- convert + write next tile into the other buffer ----
    if (pre) WRITEKV(cur ^ 1);
    cur ^= 1;
  }
#undef LOADT
#undef WRITEKV

  if (!split) {
    // ---- direct epilogue: divide by l, store fp32 ----
    #pragma unroll
    for (int r = 0; r < 4; ++r) {
      float lr  = __shfl(l_, 4 * g + r);
      float inv = 1.f / lr;
      int row   = q0 + 16 * w + 4 * g + r;
      float* op = out + ((size_t)h * SL + row) * DM + col;
      #pragma unroll
      for (int dt = 0; dt < 8; ++dt) op[dt * 16] = acc[dt][r] * inv;
    }
  } else {
    // ---- partial epilogue: unnormalized acc (bf16) to pacc; (m,l) stash ----
    char* pb = pacc + ((((size_t)(h * 32 + qb)) * 2 + z) << 14);
    #pragma unroll
    for (int r = 0; r < 4; ++r) {
      int row16 = 16 * w + 4 * g + r;
      #pragma unroll
      for (int dt = 0; dt < 8; ++dt)
        *(unsigned short*)(pb + (row16 * 128 + dt * 16 + col) * 2) = f2bfu(acc[dt][r]);
    }
    if (g == 0) {
      int row = q0 + 16 * w + col;
      *(float2*)(out + ((size_t)h * SL + row) * DM + 2 * z) = make_float2(m_, l_);
    }
  }
}

// Merge the two partials of split q-blocks. Block (h,qb): 256 threads,
// thread t -> row r=t>>2, cols (t&3)*32..+31.
__global__ __launch_bounds__(256) void attn_merge(
    const int* __restrict__ offs, int n_off,
    const char* __restrict__ pacc, float* __restrict__ out)
{
  const int t  = threadIdx.x;
  const int h  = blockIdx.x & 15;
  const int qb = blockIdx.x >> 4;
  const int q0 = qb * 64;

  int ov[8];
  #pragma unroll
  for (int ii = 0; ii < 8; ++ii) ov[ii] = (ii < n_off) ? offs[ii] : 0x7fffffff;
  int kv_lo = 0;
  #pragma unroll
  for (int ii = 0; ii < 8; ++ii) if (ov[ii] <= q0) kv_lo = max(kv_lo, ov[ii]);
  const int n = ((q0 + 64) - kv_lo) >> 6;
  if (n < 5) return;                       // not split; out already final

  const int r  = t >> 2;
  const int cq = (t & 3) * 32;
  float* orow = out + ((size_t)h * SL + q0 + r) * DM;

  float4 s = *(const float4*)orow;         // mA,lA,mB,lB stash
  __syncthreads();                         // all stash reads before any write
  float m  = fmaxf(s.x, s.z);
  float eA = __expf(s.x - m), eB = __expf(s.z - m);
  float inv = 1.f / (eA * s.y + eB * s.w);
  float fa = eA * inv, fb = eB * inv;

  const char* pA = pacc + (((size_t)(h * 32 + qb)) * 2 << 14);
  const char* pB = pA + 16384;
  #pragma unroll
  for (int j = 0; j < 4; ++j) {
    int off = (r * 128 + cq + j * 8) * 2;
    s16x8 a = *(const s16x8*)(pA + off);
    s16x8 b = *(const s16x8*)(pB + off);
    f32x4 o0, o1;
    #pragma unroll
    for (int e = 0; e < 4; ++e) o0[e] = bf2f(a[e]) * fa + bf2f(b[e]) * fb;
    #pragma unroll
    for (int e = 0; e < 4; ++e) o1[e] = bf2f(a[4 + e]) * fa + bf2f(b[4 + e]) * fb;
    *(f32x4*)(orow + cq + j * 8)     = o0;
    *(f32x4*)(orow + cq + j * 8 + 4) = o1;
  }
}

extern "C" void kernel_launch(void* const* d_in, const int* in_sizes, int n_in,
                              void* d_out, int out_size, void* d_ws, size_t ws_size,
                              hipStream_t stream) {
  const float* q = (const float*)d_in[0];
  const float* k = (const float*)d_in[1];
  const float* v = (const float*)d_in[2];
  const int* offs = (const int*)d_in[3];
  const int n_off = in_sizes[3];
  float* out = (float*)d_out;

  const size_t need = (size_t)NH * 32 * 2 * 16384;   // 16,777,216 B
  if (ws_size >= need) {
    attn_part<<<1024, 256, 0, stream>>>(q, k, v, offs, n_off, out, (char*)d_ws, 1);
    attn_merge<<<512, 256, 0, stream>>>(offs, n_off, (const char*)d_ws, out);
  } else {
    attn_part<<<512, 256, 0, stream>>>(q, k, v, offs, n_off, out, (char*)d_ws, 0);
  }
}

// Round 11
// 35.795 us; speedup vs baseline: 1.3493x; 1.3493x over previous
//
#include <hip/hip_runtime.h>
#include <hip/hip_bf16.h>
#include <math.h>

#define NH 16
#define SL 2048
#define DM 128

typedef float f32x4 __attribute__((ext_vector_type(4)));
typedef short s16x8 __attribute__((ext_vector_type(8)));
typedef short s16x4 __attribute__((ext_vector_type(4)));
typedef int   i32x4 __attribute__((ext_vector_type(4)));

static __device__ __forceinline__ unsigned short f2bfu(float f) {
  __hip_bfloat16 h = __float2bfloat16(f);
  return (unsigned short)__builtin_bit_cast(short, h);
}
static __device__ __forceinline__ short f2bf(float f) {
  __hip_bfloat16 h = __float2bfloat16(f);
  return __builtin_bit_cast(short, h);
}
static __device__ __forceinline__ unsigned pack2(float lo, float hi) {
  return (unsigned)f2bfu(lo) | ((unsigned)f2bfu(hi) << 16);
}
static __device__ __forceinline__ float bf2f(short s) {
  unsigned u = ((unsigned)(unsigned short)s) << 16;
  return __builtin_bit_cast(float, u);
}

// 4-wave block = 64 q-rows. KV tile 64. SINGLE-buffered K (row-major bf16,
// swizzled) + V^T (swizzled) = 32KB LDS -> 3 blocks/CU. Two barriers per tile
// (stage -> bar -> compute -> bar). Swapped QK^T; P->PV in-register via
// shuffles; fp32 acc. mode=1: grid 768 = split-KV partial blocks (chains<=4),
// ALL co-resident, chain-desc z-interleaved order via nibble LUTs; partial
// acc (bf16) -> pacc, (m,l) stashed in out cols 0..3; merge kernel combines.
__global__ __launch_bounds__(256) void attn_part(
    const float* __restrict__ qg,
    const float* __restrict__ kg,
    const float* __restrict__ vg,
    const int* __restrict__ offs, int n_off,
    float* __restrict__ out,
    char* __restrict__ pacc, int mode)
{
  __shared__ __align__(16) char Kb[16384];
  __shared__ __align__(16) char Vb[16384];

  const int t    = threadIdx.x;
  const int lane = t & 63;
  const int w    = t >> 6;
  const int col  = lane & 15;
  const int g    = lane >> 4;

  const int b = blockIdx.x;
  const int h = b & 15;
  int qb, z;
  bool split;
  if (mode) {
    const int s   = b >> 4;         // 0..47
    const int doc = s & 3;
    const int j   = s >> 2;         // 0..11, chain-length descending
    qb = doc * 8 + (int)((0x014245563677ull >> (4 * j)) & 15);
    const int zz = (int)((0x221201012010ull >> (4 * j)) & 15); // 0/1 half, 2 unsplit
    split = (zz != 2);
    z = zz & 1;
  } else {
    qb = 31 - ((b >> 4) & 31);
    split = false;
    z = 0;
  }
  const int q0 = qb * 64;

  const float* qh = qg + (size_t)h * SL * DM;
  const float* kh = kg + (size_t)h * SL * DM;
  const float* vh = vg + (size_t)h * SL * DM;

  const float scale = 0.08838834764831843f; // 1/sqrt(128)

  const int qrow = q0 + 16 * w + col;

  // offsets: parallel predicated loads (sorted ascending -> max of o<=pos)
  int ov[8];
  #pragma unroll
  for (int ii = 0; ii < 8; ++ii) ov[ii] = (ii < n_off) ? offs[ii] : 0x7fffffff;
  int qstart = 0, kv_lo = 0;
  #pragma unroll
  for (int ii = 0; ii < 8; ++ii) {
    if (ov[ii] <= qrow) qstart = max(qstart, ov[ii]);
    if (ov[ii] <= q0)   kv_lo  = max(kv_lo, ov[ii]);
  }
  const int n = ((q0 + 64) - kv_lo) >> 6;   // total KV tiles for this q-block

  int tA = 0, tN = n;
  if (split) {
    const int nA = (n + 1) >> 1;
    if (z) { tA = nA; tN = n - nA; } else { tN = nA; }
  }
  const int kvb = kv_lo + (tA << 6);        // this block's KV base

  // Q fragment, pre-scaled. Lane holds [row=col][k=8g+j] per 32-k group kk.
  s16x8 qf[4];
  #pragma unroll
  for (int kk = 0; kk < 4; ++kk) {
    const float* qp = qh + (size_t)qrow * DM + 32 * kk + 8 * g;
    f32x4 lo = *(const f32x4*)qp;
    f32x4 hi = *(const f32x4*)(qp + 4);
    s16x8 f;
    f[0] = f2bf(lo[0] * scale); f[1] = f2bf(lo[1] * scale);
    f[2] = f2bf(lo[2] * scale); f[3] = f2bf(lo[3] * scale);
    f[4] = f2bf(hi[0] * scale); f[5] = f2bf(hi[1] * scale);
    f[6] = f2bf(hi[2] * scale); f[7] = f2bf(hi[3] * scale);
    qf[kk] = f;
  }

  f32x4 acc[8];
  #pragma unroll
  for (int dt = 0; dt < 8; ++dt) { f32x4 zv = {0.f, 0.f, 0.f, 0.f}; acc[dt] = zv; }
  float m_ = -1e30f, l_ = 0.f;

  // staging: thread covers K rows r0+8i (cols d0..d0+3) and V rows r0*4+32k+j
  const int d0  = (t & 31) * 4;
  const int r0  = t >> 5;
  const int rot = (t >> 1) & 3;

  // P-shuffle source lanes: target (col,g) pulls from col+32*(g&1) and +16
  const int srcA = col + 32 * (g & 1);
  const int srcB = srcA + 16;
  const bool hi2 = (g >> 1) != 0;

  for (int it = 0; it < tN; ++it) {
    const int kv0 = kvb + (it << 6);

    // ---- stage K (row-major) and V (transposed), fp32 -> bf16, swizzled ----
    {
      const float* ks = kh + (size_t)kv0 * DM;
      const float* vs = vh + (size_t)kv0 * DM;
      f32x4 kr[8], vr[8];
      #pragma unroll
      for (int _i = 0; _i < 8; ++_i)
        kr[_i] = *(const f32x4*)(ks + (size_t)(r0 + 8 * _i) * DM + d0);
      #pragma unroll
      for (int _k = 0; _k < 2; ++_k) {
        #pragma unroll
        for (int _j = 0; _j < 4; ++_j)
          vr[_k * 4 + _j] = *(const f32x4*)(vs + (size_t)(r0 * 4 + 32 * _k + _j) * DM + d0);
      }
      #pragma unroll
      for (int _i = 0; _i < 8; ++_i) {
        int _r = r0 + 8 * _i;
        s16x4 _b;
        _b[0] = f2bf(kr[_i][0]); _b[1] = f2bf(kr[_i][1]);
        _b[2] = f2bf(kr[_i][2]); _b[3] = f2bf(kr[_i][3]);
        *(s16x4*)(Kb + ((_r * 256 + d0 * 2) ^ ((_r & 7) << 4))) = _b;
      }
      #pragma unroll
      for (int _k = 0; _k < 2; ++_k) {
        int _k0 = r0 * 4 + 32 * _k;
        #pragma unroll
        for (int _di = 0; _di < 4; ++_di) {
          int _dd = (_di + rot) & 3;
          int _d  = d0 + _dd;
          s16x4 _b;
          _b[0] = f2bf(vr[_k * 4 + 0][_dd]); _b[1] = f2bf(vr[_k * 4 + 1][_dd]);
          _b[2] = f2bf(vr[_k * 4 + 2][_dd]); _b[3] = f2bf(vr[_k * 4 + 3][_dd]);
          *(s16x4*)(Vb + ((_d * 128 + _k0 * 2) ^ ((_d & 7) << 4))) = _b;
        }
      }
    }
    __syncthreads();                        // staged tile visible

    // ---- QK^T (swapped): st[kt] = K_tile_kt . Q^T -> S^T[k][q] ----
    f32x4 st[4];
    #pragma unroll
    for (int kt = 0; kt < 4; ++kt) { f32x4 zv = {0.f, 0.f, 0.f, 0.f}; st[kt] = zv; }
    __builtin_amdgcn_s_setprio(1);
    #pragma unroll
    for (int kt = 0; kt < 4; ++kt) {
      int row = kt * 16 + col;
      #pragma unroll
      for (int kk = 0; kk < 4; ++kk) {
        s16x8 kf = *(const s16x8*)(Kb + ((row * 256 + 64 * kk + 16 * g) ^ ((row & 7) << 4)));
        st[kt] = __builtin_amdgcn_mfma_f32_16x16x32_bf16(kf, qf[kk], st[kt], 0, 0, 0);
      }
    }
    __builtin_amdgcn_s_setprio(0);

    // ---- mask (skipped for interior tiles) + online softmax ----
    const bool needmask = __any((kv0 + 63 > qrow) || (kv0 < qstart));
    if (needmask) {
      #pragma unroll
      for (int kt = 0; kt < 4; ++kt) {
        #pragma unroll
        for (int r = 0; r < 4; ++r) {
          int kpos = kv0 + kt * 16 + 4 * g + r;
          bool ok = (kpos <= qrow) && (kpos >= qstart);
          st[kt][r] = ok ? st[kt][r] : -3.0e38f;
        }
      }
    }
    float cm = -3.0e38f;
    #pragma unroll
    for (int kt = 0; kt < 4; ++kt) {
      #pragma unroll
      for (int r = 0; r < 4; ++r) cm = fmaxf(cm, st[kt][r]);
    }
    cm = fmaxf(cm, __shfl_xor(cm, 16));
    cm = fmaxf(cm, __shfl_xor(cm, 32));
    float mn = fmaxf(m_, cm);
    float al = __expf(m_ - mn);
    m_ = mn;
    float psum = 0.f;
    unsigned w01[4], w23[4];
    #pragma unroll
    for (int kt = 0; kt < 4; ++kt) {
      float p0 = __expf(st[kt][0] - mn);
      float p1 = __expf(st[kt][1] - mn);
      float p2 = __expf(st[kt][2] - mn);
      float p3 = __expf(st[kt][3] - mn);
      psum += (p0 + p1) + (p2 + p3);
      w01[kt] = pack2(p0, p1);
      w23[kt] = pack2(p2, p3);
    }
    psum += __shfl_xor(psum, 16);
    psum += __shfl_xor(psum, 32);
    l_ = l_ * al + psum;

    // ---- rescale O by alpha (per output row 4g+r) ----
    #pragma unroll
    for (int r = 0; r < 4; ++r) {
      float ar = __shfl(al, 4 * g + r);
      #pragma unroll
      for (int dt = 0; dt < 8; ++dt) acc[dt][r] *= ar;
    }

    // ---- PV: A-frag assembled in-register via shuffles; acc += P . V ----
    __builtin_amdgcn_s_setprio(1);
    #pragma unroll
    for (int ksel = 0; ksel < 2; ++ksel) {
      unsigned a0 = __shfl(w01[2 * ksel], srcA);
      unsigned a1 = __shfl(w01[2 * ksel + 1], srcA);
      unsigned b0 = __shfl(w23[2 * ksel], srcA);
      unsigned b1 = __shfl(w23[2 * ksel + 1], srcA);
      unsigned c0 = __shfl(w01[2 * ksel], srcB);
      unsigned c1 = __shfl(w01[2 * ksel + 1], srcB);
      unsigned e0 = __shfl(w23[2 * ksel], srcB);
      unsigned e1 = __shfl(w23[2 * ksel + 1], srcB);
      i32x4 uu;
      uu[0] = (int)(hi2 ? a1 : a0);
      uu[1] = (int)(hi2 ? b1 : b0);
      uu[2] = (int)(hi2 ? c1 : c0);
      uu[3] = (int)(hi2 ? e1 : e0);
      s16x8 pa = __builtin_bit_cast(s16x8, uu);
      #pragma unroll
      for (int dt = 0; dt < 8; ++dt) {
        int d = dt * 16 + col;
        s16x8 vf = *(const s16x8*)(Vb + ((d * 128 + 64 * ksel + 16 * g) ^ ((d & 7) << 4)));
        acc[dt] = __builtin_amdgcn_mfma_f32_16x16x32_bf16(pa, vf, acc[dt], 0, 0, 0);
      }
    }
    __builtin_amdgcn_s_setprio(0);
    __syncthreads();                        // all reads done before next stage
  }

  if (!split) {
    // ---- direct epilogue: divide by l, store fp32 ----
    #pragma unroll
    for (int r = 0; r < 4; ++r) {
      float lr  = __shfl(l_, 4 * g + r);
      float inv = 1.f / lr;
      int row   = q0 + 16 * w + 4 * g + r;
      float* op = out + ((size_t)h * SL + row) * DM + col;
      #pragma unroll
      for (int dt = 0; dt < 8; ++dt) op[dt * 16] = acc[dt][r] * inv;
    }
  } else {
    // ---- partial epilogue: unnormalized acc (bf16) to pacc; (m,l) stash ----
    char* pb = pacc + ((((size_t)(h * 32 + qb)) * 2 + z) << 14);
    #pragma unroll
    for (int r = 0; r < 4; ++r) {
      int row16 = 16 * w + 4 * g + r;
      #pragma unroll
      for (int dt = 0; dt < 8; ++dt)
        *(unsigned short*)(pb + (row16 * 128 + dt * 16 + col) * 2) = f2bfu(acc[dt][r]);
    }
    if (g == 0) {
      int row = q0 + 16 * w + col;
      *(float2*)(out + ((size_t)h * SL + row) * DM + 2 * z) = make_float2(m_, l_);
    }
  }
}

// Merge the two partials of the 256 structurally-split q-blocks.
// Block b: h=b&15, i=b>>4: doc=i&3, qb=doc*8+4+(i>>2). Thread t: row r=t>>2,
// cols (t&3)*32..+31.
__global__ __launch_bounds__(256) void attn_merge(
    const char* __restrict__ pacc, float* __restrict__ out)
{
  const int t   = threadIdx.x;
  const int b   = blockIdx.x;
  const int h   = b & 15;
  const int i   = b >> 4;
  const int qb  = (i & 3) * 8 + 4 + (i >> 2);
  const int q0  = qb * 64;

  const int r  = t >> 2;
  const int cq = (t & 3) * 32;
  float* orow = out + ((size_t)h * SL + q0 + r) * DM;

  float4 s = *(const float4*)orow;          // mA,lA,mB,lB stash
  __syncthreads();                          // all stash reads before any write
  float m  = fmaxf(s.x, s.z);
  float eA = __expf(s.x - m), eB = __expf(s.z - m);
  float inv = 1.f / (eA * s.y + eB * s.w);
  float fa = eA * inv, fb = eB * inv;

  const char* pA = pacc + (((size_t)(h * 32 + qb)) * 2 << 14);
  const char* pB = pA + 16384;
  #pragma unroll
  for (int j = 0; j < 4; ++j) {
    int off = (r * 128 + cq + j * 8) * 2;
    s16x8 a = *(const s16x8*)(pA + off);
    s16x8 bq = *(const s16x8*)(pB + off);
    f32x4 o0, o1;
    #pragma unroll
    for (int e = 0; e < 4; ++e) o0[e] = bf2f(a[e]) * fa + bf2f(bq[e]) * fb;
    #pragma unroll
    for (int e = 0; e < 4; ++e) o1[e] = bf2f(a[4 + e]) * fa + bf2f(bq[4 + e]) * fb;
    *(f32x4*)(orow + cq + j * 8)     = o0;
    *(f32x4*)(orow + cq + j * 8 + 4) = o1;
  }
}

extern "C" void kernel_launch(void* const* d_in, const int* in_sizes, int n_in,
                              void* d_out, int out_size, void* d_ws, size_t ws_size,
                              hipStream_t stream) {
  const float* q = (const float*)d_in[0];
  const float* k = (const float*)d_in[1];
  const float* v = (const float*)d_in[2];
  const int* offs = (const int*)d_in[3];
  const int n_off = in_sizes[3];
  float* out = (float*)d_out;

  const size_t need = (size_t)NH * 32 * 2 * 16384;   // 16,777,216 B
  if (ws_size >= need) {
    attn_part<<<768, 256, 0, stream>>>(q, k, v, offs, n_off, out, (char*)d_ws, 1);
    attn_merge<<<256, 256, 0, stream>>>((const char*)d_ws, out);
  } else {
    attn_part<<<512, 256, 0, stream>>>(q, k, v, offs, n_off, out, (char*)d_ws, 0);
  }
}